// Round 12
// baseline (163.803 us; speedup 1.0000x reference)
//
#include <hip/hip_runtime.h>

// ObjectMeanDirectAttention — Round 12: R11 + depth-1 x prefetch + XOR-swizzled LDS tiles.
// R11 post-mortem: AGPR-hidden registers confirmed (occ 21->43% when visible VGPR 96->44).
// Remaining: 8.4M bank-conflict cycles (stride-72 b128 pattern) + exposed HBM latency
// (prefetch was dropped in R11). Fixes:
//  - weight/Xs tiles swizzled: byte_in_row ^= (row&7)<<4  (bijective in the 128B payload)
//  - depth-1 x prefetch across q (regs free: LDS is the occupancy limiter, not VGPR)

#define NGRAPHS 4096
constexpr int LDP = 68;    // f32 LDS stride, final MLP
constexpr int LDU = 132;   // f32 LDS stride, 128-wide u tile
constexpr int LDXS = 72;   // bf16 LDS stride (144B rows) for weight + scatter tiles

typedef short bf16x8 __attribute__((ext_vector_type(8)));
typedef float f32x4 __attribute__((ext_vector_type(4)));

union BF8 { bf16x8 v; unsigned u[4]; };

__device__ __forceinline__ unsigned short f2bf(float f) {
    unsigned u = __float_as_uint(f);
    return (unsigned short)((u + 0x7FFFu + ((u >> 16) & 1u)) >> 16);  // RNE
}

__device__ __forceinline__ unsigned cvt_pk_bf16(float lo, float hi) {
    unsigned r;
    asm("v_cvt_pk_bf16_f32 %0, %1, %2" : "=v"(r) : "v"(lo), "v"(hi));
    return r;
}

__device__ __forceinline__ float bflo(unsigned u) { return __uint_as_float(u << 16); }
__device__ __forceinline__ float bfhi(unsigned u) { return __uint_as_float(u & 0xffff0000u); }

// XOR swizzle within a 144B row: payload bytes 0..127, XOR bits 4-6 with row&7
__device__ __forceinline__ int swz(int row, int byte_in_row) {
    return row * 144 + (byte_in_row ^ ((row & 7) << 4));
}

__device__ __forceinline__ int lower_bound_i(const int* __restrict__ arr, int n, int v) {
    int lo = 0, hi = n;
    while (lo < hi) {
        int mid = (lo + hi) >> 1;
        if (arr[mid] < v) lo = mid + 1; else hi = mid;
    }
    return lo;
}

// one-shot prep (unchanged): permuted bf16 weights + packed coefs into ws
__global__ __launch_bounds__(256)
void prep_kernel(const float* __restrict__ W1, const float* __restrict__ W2,
                 const float* __restrict__ b1, const float* __restrict__ b2,
                 const float* __restrict__ W3,
                 unsigned short* __restrict__ w1p, unsigned short* __restrict__ w2t,
                 unsigned* __restrict__ coefpk) {
    int e = blockIdx.x * 256 + threadIdx.x;     // 0..4095
    int r = e >> 6, k = e & 63;
    int ct = r >> 4, kb = (r >> 2) & 3, reg = r & 3;
    int pi = 32 * (ct >> 1) + 8 * kb + 4 * (ct & 1) + reg;
    w1p[e] = f2bf(W1[k * 64 + pi]);
    w2t[e] = f2bf(W2[k * 64 + r]);
    if (blockIdx.x == 0) {
        int t = threadIdx.x;
        if (t < 32) {
            int kb2 = t >> 3, ct2 = (t >> 1) & 3, j = t & 1;
            int base = 32 * (ct2 >> 1) + 4 * (ct2 & 1) + 8 * kb2 + 2 * j;
            coefpk[t] = ((unsigned)f2bf(b1[base + 1]) << 16) | (unsigned)f2bf(b1[base]);
        } else if (t < 96) {
            int e2 = t - 32;
            int kb2 = e2 >> 4, ct2 = (e2 >> 2) & 3, rg = e2 & 3;
            int idx = ct2 * 16 + 4 * kb2 + rg;
            coefpk[t] = ((unsigned)f2bf(W3[idx]) << 16) | (unsigned)f2bf(b2[idx]);
        }
    }
}

// ---------------- attention MLP + weighted scatter ----------------
__global__ __launch_bounds__(256)
void attn_scatter_mfma(const float* __restrict__ x1, const int* __restrict__ batch1, int N1, int nblk1,
                       const float* __restrict__ x2, const int* __restrict__ batch2, int N2,
                       const unsigned short* __restrict__ w1p, const unsigned short* __restrict__ w2t,
                       const unsigned* __restrict__ coefpk, const float* __restrict__ b3,
                       float* __restrict__ num) {
    __shared__ alignas(16) unsigned short W1L[64 * LDXS];     // bf16, swizzled 144B rows
    __shared__ alignas(16) unsigned short W2L[64 * LDXS];
    __shared__ alignas(16) unsigned coefL[96];
    __shared__ alignas(16) unsigned short Xs[4][16 * LDXS];   // per-wave scatter tile, swizzled

    const float* x; const int* batch; int N, col_off, blk;
    if ((int)blockIdx.x < nblk1) { x = x1; batch = batch1; N = N1; col_off = 0;  blk = blockIdx.x; }
    else                         { x = x2; batch = batch2; N = N2; col_off = 64; blk = blockIdx.x - nblk1; }

    const int t = threadIdx.x;
    const int w = t >> 6, l = t & 63;
    const int jj = l & 15, kb = l >> 4;
    const int base = blk * 256 + w * 64;          // this wave's 64 nodes

    // ---- stage weights (16 KB) + coefs into LDS, swizzled rows ----
    {
        const uint4* s1 = (const uint4*)w1p;      // 512 chunks of 16B
        const uint4* s2 = (const uint4*)w2t;
#pragma unroll
        for (int r = 0; r < 2; ++r) {
            int e4 = t + 256 * r;                 // 0..511
            int row = e4 >> 3, c4 = e4 & 7;       // row 0..63, 16B-chunk 0..7
            int off = swz(row, c4 * 16);
            *(uint4*)((char*)W1L + off) = s1[e4];
            *(uint4*)((char*)W2L + off) = s2[e4];
        }
        if (t < 96) coefL[t] = coefpk[t];
    }
    __syncthreads();

    const bool wave_valid = (base < N);
    const int nvalid = wave_valid ? min(64, N - base) : 0;

    // ---- batch ids + segment ballot ----
    const int gball = batch[min(base + l, N - 1)];
    const int gprev = __shfl_up(gball, 1);
    const unsigned long long bal = __ballot(l > 0 && gball != gprev);
    const bool slow = (bal != 0ull) || (nvalid < 64);

    const float b3v = b3[0];
    unsigned short* Xw = Xs[w];

    float ac0 = 0.f, ac1 = 0.f, ac2 = 0.f, ac3 = 0.f;   // fast path (4 feats x own nodes)
    float sacc = 0.f;                                    // slow path (feature l)
    int gcur = __shfl(gball, 0);

    // swizzled byte offsets this lane uses every q
    const int wOff0 = swz(jj, kb * 16) - jj * 144;        // within-row part for row&7 == jj&7
    const int wOff1 = swz(jj, kb * 16 + 64) - jj * 144;

    // ---- prologue: q=0 x loads ----
    float4 c0, c1, c2, c3;
    {
        const int row = base + jj;
        c0 = c1 = c2 = c3 = make_float4(0.f, 0.f, 0.f, 0.f);
        if (row < N) {
            const float* xr = x + (size_t)row * 64;
            c0 = *(const float4*)&xr[kb * 8];
            c1 = *(const float4*)&xr[kb * 8 + 4];
            c2 = *(const float4*)&xr[32 + kb * 8];
            c3 = *(const float4*)&xr[32 + kb * 8 + 4];
        }
    }

#pragma unroll
    for (int q = 0; q < 4; ++q) {
        const int nbase = base + q * 16;

        // ---- issue q+1 loads FIRST (keeps next 4KB/wave in flight under compute) ----
        float4 n0, n1, n2, n3;
        n0 = n1 = n2 = n3 = make_float4(0.f, 0.f, 0.f, 0.f);
        if (q < 3) {
            const int rown = nbase + 16 + jj;
            if (rown < N) {
                const float* xr = x + (size_t)rown * 64;
                n0 = *(const float4*)&xr[kb * 8];
                n1 = *(const float4*)&xr[kb * 8 + 4];
                n2 = *(const float4*)&xr[32 + kb * 8];
                n3 = *(const float4*)&xr[32 + kb * 8 + 4];
            }
        }

        // ---- convert current q, stash swizzled scatter tile ----
        BF8 xb0, xb1;
        xb0.u[0] = cvt_pk_bf16(c0.x, c0.y); xb0.u[1] = cvt_pk_bf16(c0.z, c0.w);
        xb0.u[2] = cvt_pk_bf16(c1.x, c1.y); xb0.u[3] = cvt_pk_bf16(c1.z, c1.w);
        xb1.u[0] = cvt_pk_bf16(c2.x, c2.y); xb1.u[1] = cvt_pk_bf16(c2.z, c2.w);
        xb1.u[2] = cvt_pk_bf16(c3.x, c3.y); xb1.u[3] = cvt_pk_bf16(c3.z, c3.w);
        *(bf16x8*)((char*)Xw + jj * 144 + wOff0) = xb0.v;
        *(bf16x8*)((char*)Xw + jj * 144 + wOff1) = xb1.v;

        // ---- layer 1 (swapped): operands from swizzled LDS ----
        unsigned ph[8];
#pragma unroll
        for (int ct = 0; ct < 4; ++ct) {
            const char* wr = (const char*)W1L + (ct * 16 + jj) * 144;
            const bf16x8 wf0 = *(const bf16x8*)(wr + wOff0);
            const bf16x8 wf1 = *(const bf16x8*)(wr + wOff1);
            const uint2 b1c = *(const uint2*)&coefL[(kb * 4 + ct) * 2];
            f32x4 acc = { bflo(b1c.x), bfhi(b1c.x), bflo(b1c.y), bfhi(b1c.y) };
            acc = __builtin_amdgcn_mfma_f32_16x16x32_bf16(wf0, xb0.v, acc, 0, 0, 0);
            acc = __builtin_amdgcn_mfma_f32_16x16x32_bf16(wf1, xb1.v, acc, 0, 0, 0);
            ph[2 * ct]     = cvt_pk_bf16(fmaxf(acc[0], 0.f), fmaxf(acc[1], 0.f));
            ph[2 * ct + 1] = cvt_pk_bf16(fmaxf(acc[2], 0.f), fmaxf(acc[3], 0.f));
        }
        BF8 bh0, bh1;
        bh0.u[0] = ph[0]; bh0.u[1] = ph[1]; bh0.u[2] = ph[2]; bh0.u[3] = ph[3];
        bh1.u[0] = ph[4]; bh1.u[1] = ph[5]; bh1.u[2] = ph[6]; bh1.u[7 - 7] = bh1.u[0]; // no-op guard
        bh1.u[0] = ph[4]; bh1.u[1] = ph[5]; bh1.u[2] = ph[6]; bh1.u[3] = ph[7];

        // ---- layer 2+3 (swapped): operands from swizzled LDS ----
        float p = 0.f;
#pragma unroll
        for (int ct = 0; ct < 4; ++ct) {
            const char* wr = (const char*)W2L + (ct * 16 + jj) * 144;
            const bf16x8 wf0 = *(const bf16x8*)(wr + wOff0);
            const bf16x8 wf1 = *(const bf16x8*)(wr + wOff1);
            f32x4 acc = { 0.f, 0.f, 0.f, 0.f };
            acc = __builtin_amdgcn_mfma_f32_16x16x32_bf16(wf0, bh0.v, acc, 0, 0, 0);
            acc = __builtin_amdgcn_mfma_f32_16x16x32_bf16(wf1, bh1.v, acc, 0, 0, 0);
            const uint4 bwc = *(const uint4*)&coefL[32 + (kb * 4 + ct) * 4];
            p += fmaxf(acc[0] + bflo(bwc.x), 0.f) * bfhi(bwc.x)
               + fmaxf(acc[1] + bflo(bwc.y), 0.f) * bfhi(bwc.y)
               + fmaxf(acc[2] + bflo(bwc.z), 0.f) * bfhi(bwc.z)
               + fmaxf(acc[3] + bflo(bwc.w), 0.f) * bfhi(bwc.w);
        }
        p += __shfl_xor(p, 16);
        p += __shfl_xor(p, 32);
        const float a = p + b3v;     // a[node jj], all kb copies

        // ---- scatter ----
        if (!slow) {
            // lane (jj,kb): features jj*4..+3, nodes kb*4..+3 of this q-chunk
#pragma unroll
            for (int j = 0; j < 4; ++j) {
                const int row = kb * 4 + j;
                const float aj = __shfl(a, row);
                const uint2 xr2 = *(const uint2*)((char*)Xw + swz(row, jj * 8));
                ac0 += bflo(xr2.x) * aj;
                ac1 += bfhi(xr2.x) * aj;
                ac2 += bflo(xr2.y) * aj;
                ac3 += bfhi(xr2.y) * aj;
            }
        } else if (wave_valid) {
            const int lim = min(16, N - nbase);
#pragma unroll
            for (int i = 0; i < 16; ++i) {
                if (i < lim) {                              // wave-uniform
                    const int g = __shfl(gball, q * 16 + i);
                    const float ai = __shfl(a, i);
                    if (g != gcur) {
                        atomicAdd(&num[(size_t)gcur * 128 + col_off + l], sacc);
                        sacc = 0.f;
                        gcur = g;
                    }
                    const unsigned xv = *(const unsigned short*)((char*)Xw + swz(i, l * 2));
                    sacc += __uint_as_float(xv << 16) * ai;
                }
            }
        }

        // rotate prefetch buffers
        c0 = n0; c1 = n1; c2 = n2; c3 = n3;
    }

    // ---- final flush ----
    if (!slow) {
        ac0 += __shfl_xor(ac0, 16); ac1 += __shfl_xor(ac1, 16);
        ac2 += __shfl_xor(ac2, 16); ac3 += __shfl_xor(ac3, 16);
        ac0 += __shfl_xor(ac0, 32); ac1 += __shfl_xor(ac1, 32);
        ac2 += __shfl_xor(ac2, 32); ac3 += __shfl_xor(ac3, 32);
        if (kb == 0) {
            const int g = __shfl(gball, 0);
            float* dst = &num[(size_t)g * 128 + col_off + jj * 4];
            atomicAdd(dst + 0, ac0);
            atomicAdd(dst + 1, ac1);
            atomicAdd(dst + 2, ac2);
            atomicAdd(dst + 3, ac3);
        }
    } else if (wave_valid) {
        atomicAdd(&num[(size_t)gcur * 128 + col_off + l], sacc);
    }
}

// ---------------- final MLP (f32, unchanged: negligible time) ----------------
template<int K, int LDAa, int LDBb>
__device__ __forceinline__ void tile_gemm(const float* __restrict__ As,
                                          const float* __restrict__ Bs,
                                          float acc[4][4], int n0, int j0) {
#pragma unroll 4
    for (int k0 = 0; k0 < K; k0 += 4) {
        float4 a[4], wv[4];
#pragma unroll
        for (int i = 0; i < 4; i++) a[i] = *(const float4*)&As[(n0 + i) * LDAa + k0];
#pragma unroll
        for (int kk = 0; kk < 4; kk++) wv[kk] = *(const float4*)&Bs[(k0 + kk) * LDBb + j0];
#pragma unroll
        for (int i = 0; i < 4; i++) {
            const float av0 = a[i].x, av1 = a[i].y, av2 = a[i].z, av3 = a[i].w;
            acc[i][0] += av0 * wv[0].x; acc[i][1] += av0 * wv[0].y; acc[i][2] += av0 * wv[0].z; acc[i][3] += av0 * wv[0].w;
            acc[i][0] += av1 * wv[1].x; acc[i][1] += av1 * wv[1].y; acc[i][2] += av1 * wv[1].z; acc[i][3] += av1 * wv[1].w;
            acc[i][0] += av2 * wv[2].x; acc[i][1] += av2 * wv[2].y; acc[i][2] += av2 * wv[2].z; acc[i][3] += av2 * wv[2].w;
            acc[i][0] += av3 * wv[3].x; acc[i][1] += av3 * wv[3].y; acc[i][2] += av3 * wv[3].z; acc[i][3] += av3 * wv[3].w;
        }
    }
}

__global__ __launch_bounds__(256)
void final_mlp_kernel(const float* __restrict__ num,
                      const int* __restrict__ batch1, int N1,
                      const int* __restrict__ batch2, int N2,
                      const float* __restrict__ W1, const float* __restrict__ b1,  // [128][64]
                      const float* __restrict__ W2, const float* __restrict__ b2,  // [64][64]
                      const float* __restrict__ W3, const float* __restrict__ b3,  // [64][64]
                      float* __restrict__ out) {
    __shared__ float Us[64 * LDU];
    __shared__ float W1s[128 * LDP];
    __shared__ float W2s[64 * LDP];
    __shared__ float W3s[64 * LDP];
    __shared__ float Hs[64 * LDP];
    __shared__ float inv1[64], inv2[64];

    const int t = threadIdx.x;
    const int rowbase = blockIdx.x * 64;

    if (t < 64) {
        int g = rowbase + t;
        int c = lower_bound_i(batch1, N1, g + 1) - lower_bound_i(batch1, N1, g);
        inv1[t] = 1.0f / (float)max(c, 1);
    } else if (t < 128) {
        int g = rowbase + (t - 64);
        int c = lower_bound_i(batch2, N2, g + 1) - lower_bound_i(batch2, N2, g);
        inv2[t - 64] = 1.0f / (float)max(c, 1);
    }

    {
        const float4* W1v = (const float4*)W1;
#pragma unroll
        for (int r = 0; r < 8; r++) {
            int e4 = t + 256 * r;
            int e = e4 * 4;
            int k = e / 64, j = e % 64;
            *(float4*)&W1s[k * LDP + j] = W1v[e4];
        }
        const float4* W2v = (const float4*)W2;
        const float4* W3v = (const float4*)W3;
#pragma unroll
        for (int r = 0; r < 4; r++) {
            int e4 = t + 256 * r;
            int e = e4 * 4;
            int k = e / 64, j = e % 64;
            *(float4*)&W2s[k * LDP + j] = W2v[e4];
            *(float4*)&W3s[k * LDP + j] = W3v[e4];
        }
    }
    __syncthreads();

    {
        const float4* nv = (const float4*)(num + (size_t)rowbase * 128);
#pragma unroll
        for (int r = 0; r < 8; r++) {
            int e4 = t + 256 * r;
            int e = e4 * 4;
            int row = e / 128, col = e % 128;
            float4 v = nv[e4];
            float s = (col < 64) ? inv1[row] : inv2[row];
            v.x *= s; v.y *= s; v.z *= s; v.w *= s;
            *(float4*)&Us[row * LDU + col] = v;
        }
    }
    __syncthreads();

    const int fg = t & 15, ng = t >> 4;
    const int j0 = fg * 4, n0 = ng * 4;

    float acc[4][4];
#pragma unroll
    for (int i = 0; i < 4; i++) { acc[i][0] = 0.f; acc[i][1] = 0.f; acc[i][2] = 0.f; acc[i][3] = 0.f; }
    tile_gemm<128, LDU, LDP>(Us, W1s, acc, n0, j0);
    {
        float4 bb = *(const float4*)&b1[j0];
#pragma unroll
        for (int i = 0; i < 4; i++) {
            float4 hv;
            hv.x = fmaxf(acc[i][0] + bb.x, 0.f);
            hv.y = fmaxf(acc[i][1] + bb.y, 0.f);
            hv.z = fmaxf(acc[i][2] + bb.z, 0.f);
            hv.w = fmaxf(acc[i][3] + bb.w, 0.f);
            *(float4*)&Hs[(n0 + i) * LDP + j0] = hv;
        }
    }
    __syncthreads();

#pragma unroll
    for (int i = 0; i < 4; i++) { acc[i][0] = 0.f; acc[i][1] = 0.f; acc[i][2] = 0.f; acc[i][3] = 0.f; }
    tile_gemm<64, LDP, LDP>(Hs, W2s, acc, n0, j0);
    {
        float4 bb = *(const float4*)&b2[j0];
#pragma unroll
        for (int i = 0; i < 4; i++) {
            float4 hv;
            hv.x = fmaxf(acc[i][0] + bb.x, 0.f);
            hv.y = fmaxf(acc[i][1] + bb.y, 0.f);
            hv.z = fmaxf(acc[i][2] + bb.z, 0.f);
            hv.w = fmaxf(acc[i][3] + bb.w, 0.f);
            *(float4*)&Us[(n0 + i) * LDU + j0] = hv;
        }
    }
    __syncthreads();

#pragma unroll
    for (int i = 0; i < 4; i++) { acc[i][0] = 0.f; acc[i][1] = 0.f; acc[i][2] = 0.f; acc[i][3] = 0.f; }
    tile_gemm<64, LDU, LDP>(Us, W3s, acc, n0, j0);
    {
        float4 bb = *(const float4*)&b3[j0];
#pragma unroll
        for (int i = 0; i < 4; i++) {
            float4 ov;
            ov.x = acc[i][0] + bb.x;
            ov.y = acc[i][1] + bb.y;
            ov.z = acc[i][2] + bb.z;
            ov.w = acc[i][3] + bb.w;
            *(float4*)&out[(size_t)(rowbase + n0 + i) * 64 + j0] = ov;
        }
    }
}

extern "C" void kernel_launch(void* const* d_in, const int* in_sizes, int n_in,
                              void* d_out, int out_size, void* d_ws, size_t ws_size,
                              hipStream_t stream) {
    const float* x1     = (const float*)d_in[0];
    const int*   batch1 = (const int*)d_in[1];
    const float* x2     = (const float*)d_in[2];
    const int*   batch2 = (const int*)d_in[3];
    const float* aW1    = (const float*)d_in[4];
    const float* ab1    = (const float*)d_in[5];
    const float* aW2    = (const float*)d_in[6];
    const float* ab2    = (const float*)d_in[7];
    const float* aW3    = (const float*)d_in[8];
    const float* ab3    = (const float*)d_in[9];
    const float* fW1    = (const float*)d_in[10];
    const float* fb1    = (const float*)d_in[11];
    const float* fW2    = (const float*)d_in[12];
    const float* fb2    = (const float*)d_in[13];
    const float* fW3    = (const float*)d_in[14];
    const float* fb3    = (const float*)d_in[15];

    const int N1 = in_sizes[0] / 64;
    const int N2 = in_sizes[2] / 64;

    // ws layout: [w1p 8KB][w2t 8KB][coefpk 1KB][num f32 4096x128 = 2MB]
    unsigned short* w1p = (unsigned short*)d_ws;
    unsigned short* w2t = w1p + 64 * 64;
    unsigned* coefpk = (unsigned*)((char*)d_ws + 16384);
    float* num = (float*)((char*)d_ws + 17408);

    prep_kernel<<<dim3(16), dim3(256), 0, stream>>>(aW1, aW2, ab1, ab2, aW3, w1p, w2t, coefpk);
    hipMemsetAsync(num, 0, (size_t)NGRAPHS * 128 * sizeof(float), stream);

    const int nblk1 = (N1 + 255) / 256;
    const int nblk2 = (N2 + 255) / 256;
    attn_scatter_mfma<<<dim3(nblk1 + nblk2), dim3(256), 0, stream>>>(
        x1, batch1, N1, nblk1, x2, batch2, N2,
        w1p, w2t, coefpk, ab3, num);
    final_mlp_kernel<<<dim3(NGRAPHS / 64), dim3(256), 0, stream>>>(
        num, batch1, N1, batch2, N2, fW1, fb1, fW2, fb2, fW3, fb3, (float*)d_out);
}

// Round 13
// 155.590 us; speedup vs baseline: 1.0528x; 1.0528x over previous
//
#include <hip/hip_runtime.h>

// ObjectMeanDirectAttention — Round 13: revert swizzle (R12's made conflicts 3x WORSE —
// the unswizzled b128 pattern was already bank-uniform); keep depth-1 prefetch;
// coefficients staged as raw f32 in LDS (pi-order makes all three contiguous f32x4
// reads) — removes ~192 unpack VALU/wave and 24 coef registers.

#define NGRAPHS 4096
constexpr int LDP = 68;    // f32 LDS stride, final MLP
constexpr int LDU = 132;   // f32 LDS stride, 128-wide u tile
constexpr int LDXS = 72;   // bf16 LDS stride (144B rows) for weight + scatter tiles

typedef short bf16x8 __attribute__((ext_vector_type(8)));
typedef float f32x4 __attribute__((ext_vector_type(4)));

union BF8 { bf16x8 v; unsigned u[4]; };

__device__ __forceinline__ unsigned short f2bf(float f) {
    unsigned u = __float_as_uint(f);
    return (unsigned short)((u + 0x7FFFu + ((u >> 16) & 1u)) >> 16);  // RNE
}

__device__ __forceinline__ unsigned cvt_pk_bf16(float lo, float hi) {
    unsigned r;
    asm("v_cvt_pk_bf16_f32 %0, %1, %2" : "=v"(r) : "v"(lo), "v"(hi));
    return r;
}

__device__ __forceinline__ float bflo(unsigned u) { return __uint_as_float(u << 16); }
__device__ __forceinline__ float bfhi(unsigned u) { return __uint_as_float(u & 0xffff0000u); }

__device__ __forceinline__ int lower_bound_i(const int* __restrict__ arr, int n, int v) {
    int lo = 0, hi = n;
    while (lo < hi) {
        int mid = (lo + hi) >> 1;
        if (arr[mid] < v) lo = mid + 1; else hi = mid;
    }
    return lo;
}

// one-shot prep: permuted bf16 weights into ws
//   w1p[r*64+k] = bf16(W1[k][pi(r)]), pi(16ct+4kb+reg) = 32*(ct>>1)+8kb+4*(ct&1)+reg
//   w2t[r*64+k] = bf16(W2[k][r])
__global__ __launch_bounds__(256)
void prep_kernel(const float* __restrict__ W1, const float* __restrict__ W2,
                 unsigned short* __restrict__ w1p, unsigned short* __restrict__ w2t) {
    int e = blockIdx.x * 256 + threadIdx.x;     // 0..4095
    int r = e >> 6, k = e & 63;
    int ct = r >> 4, kb = (r >> 2) & 3, reg = r & 3;
    int pi = 32 * (ct >> 1) + 8 * kb + 4 * (ct & 1) + reg;
    w1p[e] = f2bf(W1[k * 64 + pi]);
    w2t[e] = f2bf(W2[k * 64 + r]);
}

// ---------------- attention MLP + weighted scatter ----------------
__global__ __launch_bounds__(256)
void attn_scatter_mfma(const float* __restrict__ x1, const int* __restrict__ batch1, int N1, int nblk1,
                       const float* __restrict__ x2, const int* __restrict__ batch2, int N2,
                       const unsigned short* __restrict__ w1p, const unsigned short* __restrict__ w2t,
                       const float* __restrict__ b1, const float* __restrict__ b2,
                       const float* __restrict__ W3, const float* __restrict__ b3,
                       float* __restrict__ num) {
    __shared__ alignas(16) unsigned short W1L[64 * LDXS];     // bf16, 144B rows (bank-uniform)
    __shared__ alignas(16) unsigned short W2L[64 * LDXS];
    __shared__ alignas(16) float coefF[192];                  // [0..63]=b1(f32), [64..127]=b2, [128..191]=W3
    __shared__ alignas(16) unsigned short Xs[4][16 * LDXS];   // per-wave bf16 scatter tile

    const float* x; const int* batch; int N, col_off, blk;
    if ((int)blockIdx.x < nblk1) { x = x1; batch = batch1; N = N1; col_off = 0;  blk = blockIdx.x; }
    else                         { x = x2; batch = batch2; N = N2; col_off = 64; blk = blockIdx.x - nblk1; }

    const int t = threadIdx.x;
    const int w = t >> 6, l = t & 63;
    const int jj = l & 15, kb = l >> 4;
    const int base = blk * 256 + w * 64;          // this wave's 64 nodes

    // ---- stage weights (16 KB) + f32 coefficients into LDS ----
    {
        const uint4* s1 = (const uint4*)w1p;      // 512 chunks of 16B
        const uint4* s2 = (const uint4*)w2t;
#pragma unroll
        for (int r = 0; r < 2; ++r) {
            int e4 = t + 256 * r;                 // 0..511
            int row = e4 >> 3, c4 = e4 & 7;       // row 0..63, 16B-chunk 0..7
            *(uint4*)((char*)W1L + row * 144 + c4 * 16) = s1[e4];
            *(uint4*)((char*)W2L + row * 144 + c4 * 16) = s2[e4];
        }
        if (t < 64)       coefF[t] = b1[t];
        else if (t < 128) coefF[t] = b2[t - 64];
        else if (t < 192) coefF[t] = W3[t - 128];
    }
    __syncthreads();

    const bool wave_valid = (base < N);
    const int nvalid = wave_valid ? min(64, N - base) : 0;

    // ---- batch ids + segment ballot ----
    const int gball = batch[min(base + l, N - 1)];
    const int gprev = __shfl_up(gball, 1);
    const unsigned long long bal = __ballot(l > 0 && gball != gprev);
    const bool slow = (bal != 0ull) || (nvalid < 64);

    const float b3v = b3[0];
    unsigned short* Xw = Xs[w];

    float ac0 = 0.f, ac1 = 0.f, ac2 = 0.f, ac3 = 0.f;   // fast path (4 feats x own nodes)
    float sacc = 0.f;                                    // slow path (feature l)
    int gcur = __shfl(gball, 0);

    // ---- prologue: q=0 x loads ----
    float4 c0, c1, c2, c3;
    {
        const int row = base + jj;
        c0 = c1 = c2 = c3 = make_float4(0.f, 0.f, 0.f, 0.f);
        if (row < N) {
            const float* xr = x + (size_t)row * 64;
            c0 = *(const float4*)&xr[kb * 8];
            c1 = *(const float4*)&xr[kb * 8 + 4];
            c2 = *(const float4*)&xr[32 + kb * 8];
            c3 = *(const float4*)&xr[32 + kb * 8 + 4];
        }
    }

#pragma unroll
    for (int q = 0; q < 4; ++q) {
        const int nbase = base + q * 16;

        // ---- issue q+1 loads FIRST (keeps next 4KB/wave in flight under compute) ----
        float4 n0, n1, n2, n3;
        n0 = n1 = n2 = n3 = make_float4(0.f, 0.f, 0.f, 0.f);
        if (q < 3) {
            const int rown = nbase + 16 + jj;
            if (rown < N) {
                const float* xr = x + (size_t)rown * 64;
                n0 = *(const float4*)&xr[kb * 8];
                n1 = *(const float4*)&xr[kb * 8 + 4];
                n2 = *(const float4*)&xr[32 + kb * 8];
                n3 = *(const float4*)&xr[32 + kb * 8 + 4];
            }
        }

        // ---- convert current q, stash scatter tile ----
        BF8 xb0, xb1;
        xb0.u[0] = cvt_pk_bf16(c0.x, c0.y); xb0.u[1] = cvt_pk_bf16(c0.z, c0.w);
        xb0.u[2] = cvt_pk_bf16(c1.x, c1.y); xb0.u[3] = cvt_pk_bf16(c1.z, c1.w);
        xb1.u[0] = cvt_pk_bf16(c2.x, c2.y); xb1.u[1] = cvt_pk_bf16(c2.z, c2.w);
        xb1.u[2] = cvt_pk_bf16(c3.x, c3.y); xb1.u[3] = cvt_pk_bf16(c3.z, c3.w);
        *(bf16x8*)&Xw[jj * LDXS + kb * 8]      = xb0.v;
        *(bf16x8*)&Xw[jj * LDXS + 32 + kb * 8] = xb1.v;

        // ---- layer 1 (swapped): weights from LDS, bias C-init from f32 LDS ----
        unsigned ph[8];
#pragma unroll
        for (int ct = 0; ct < 4; ++ct) {
            const unsigned short* wr = &W1L[(ct * 16 + jj) * LDXS + kb * 8];
            const bf16x8 wf0 = *(const bf16x8*)wr;
            const bf16x8 wf1 = *(const bf16x8*)(wr + 32);
            f32x4 acc = *(const f32x4*)&coefF[32 * (ct >> 1) + 8 * kb + 4 * (ct & 1)];
            acc = __builtin_amdgcn_mfma_f32_16x16x32_bf16(wf0, xb0.v, acc, 0, 0, 0);
            acc = __builtin_amdgcn_mfma_f32_16x16x32_bf16(wf1, xb1.v, acc, 0, 0, 0);
            ph[2 * ct]     = cvt_pk_bf16(fmaxf(acc[0], 0.f), fmaxf(acc[1], 0.f));
            ph[2 * ct + 1] = cvt_pk_bf16(fmaxf(acc[2], 0.f), fmaxf(acc[3], 0.f));
        }
        BF8 bh0, bh1;
        bh0.u[0] = ph[0]; bh0.u[1] = ph[1]; bh0.u[2] = ph[2]; bh0.u[3] = ph[3];
        bh1.u[0] = ph[4]; bh1.u[1] = ph[5]; bh1.u[2] = ph[6]; bh1.u[3] = ph[7];

        // ---- layer 2+3 (swapped): b2/W3 as f32x4 from LDS ----
        float p = 0.f;
#pragma unroll
        for (int ct = 0; ct < 4; ++ct) {
            const unsigned short* wr = &W2L[(ct * 16 + jj) * LDXS + kb * 8];
            const bf16x8 wf0 = *(const bf16x8*)wr;
            const bf16x8 wf1 = *(const bf16x8*)(wr + 32);
            f32x4 acc = { 0.f, 0.f, 0.f, 0.f };
            acc = __builtin_amdgcn_mfma_f32_16x16x32_bf16(wf0, bh0.v, acc, 0, 0, 0);
            acc = __builtin_amdgcn_mfma_f32_16x16x32_bf16(wf1, bh1.v, acc, 0, 0, 0);
            const f32x4 b2v = *(const f32x4*)&coefF[64 + ct * 16 + 4 * kb];
            const f32x4 w3v = *(const f32x4*)&coefF[128 + ct * 16 + 4 * kb];
            p += fmaxf(acc[0] + b2v[0], 0.f) * w3v[0]
               + fmaxf(acc[1] + b2v[1], 0.f) * w3v[1]
               + fmaxf(acc[2] + b2v[2], 0.f) * w3v[2]
               + fmaxf(acc[3] + b2v[3], 0.f) * w3v[3];
        }
        p += __shfl_xor(p, 16);
        p += __shfl_xor(p, 32);
        const float a = p + b3v;     // a[node jj], all kb copies

        // ---- scatter ----
        if (!slow) {
            // lane (jj,kb): features jj*4..+3, nodes kb*4..+3 of this q-chunk
#pragma unroll
            for (int j = 0; j < 4; ++j) {
                const int row = kb * 4 + j;
                const float aj = __shfl(a, row);
                const uint2 xr2 = *(const uint2*)&Xw[row * LDXS + jj * 4];
                ac0 += bflo(xr2.x) * aj;
                ac1 += bfhi(xr2.x) * aj;
                ac2 += bflo(xr2.y) * aj;
                ac3 += bfhi(xr2.y) * aj;
            }
        } else if (wave_valid) {
            const int lim = min(16, N - nbase);
#pragma unroll
            for (int i = 0; i < 16; ++i) {
                if (i < lim) {                              // wave-uniform
                    const int g = __shfl(gball, q * 16 + i);
                    const float ai = __shfl(a, i);
                    if (g != gcur) {
                        atomicAdd(&num[(size_t)gcur * 128 + col_off + l], sacc);
                        sacc = 0.f;
                        gcur = g;
                    }
                    sacc += __uint_as_float(((unsigned)Xw[i * LDXS + l]) << 16) * ai;
                }
            }
        }

        // rotate prefetch buffers
        c0 = n0; c1 = n1; c2 = n2; c3 = n3;
    }

    // ---- final flush ----
    if (!slow) {
        ac0 += __shfl_xor(ac0, 16); ac1 += __shfl_xor(ac1, 16);
        ac2 += __shfl_xor(ac2, 16); ac3 += __shfl_xor(ac3, 16);
        ac0 += __shfl_xor(ac0, 32); ac1 += __shfl_xor(ac1, 32);
        ac2 += __shfl_xor(ac2, 32); ac3 += __shfl_xor(ac3, 32);
        if (kb == 0) {
            const int g = __shfl(gball, 0);
            float* dst = &num[(size_t)g * 128 + col_off + jj * 4];
            atomicAdd(dst + 0, ac0);
            atomicAdd(dst + 1, ac1);
            atomicAdd(dst + 2, ac2);
            atomicAdd(dst + 3, ac3);
        }
    } else if (wave_valid) {
        atomicAdd(&num[(size_t)gcur * 128 + col_off + l], sacc);
    }
}

// ---------------- final MLP (f32, unchanged: negligible time) ----------------
template<int K, int LDAa, int LDBb>
__device__ __forceinline__ void tile_gemm(const float* __restrict__ As,
                                          const float* __restrict__ Bs,
                                          float acc[4][4], int n0, int j0) {
#pragma unroll 4
    for (int k0 = 0; k0 < K; k0 += 4) {
        float4 a[4], wv[4];
#pragma unroll
        for (int i = 0; i < 4; i++) a[i] = *(const float4*)&As[(n0 + i) * LDAa + k0];
#pragma unroll
        for (int kk = 0; kk < 4; kk++) wv[kk] = *(const float4*)&Bs[(k0 + kk) * LDBb + j0];
#pragma unroll
        for (int i = 0; i < 4; i++) {
            const float av0 = a[i].x, av1 = a[i].y, av2 = a[i].z, av3 = a[i].w;
            acc[i][0] += av0 * wv[0].x; acc[i][1] += av0 * wv[0].y; acc[i][2] += av0 * wv[0].z; acc[i][3] += av0 * wv[0].w;
            acc[i][0] += av1 * wv[1].x; acc[i][1] += av1 * wv[1].y; acc[i][2] += av1 * wv[1].z; acc[i][3] += av1 * wv[1].w;
            acc[i][0] += av2 * wv[2].x; acc[i][1] += av2 * wv[2].y; acc[i][2] += av2 * wv[2].z; acc[i][3] += av2 * wv[2].w;
            acc[i][0] += av3 * wv[3].x; acc[i][1] += av3 * wv[3].y; acc[i][2] += av3 * wv[3].z; acc[i][3] += av3 * wv[3].w;
        }
    }
}

__global__ __launch_bounds__(256)
void final_mlp_kernel(const float* __restrict__ num,
                      const int* __restrict__ batch1, int N1,
                      const int* __restrict__ batch2, int N2,
                      const float* __restrict__ W1, const float* __restrict__ b1,  // [128][64]
                      const float* __restrict__ W2, const float* __restrict__ b2,  // [64][64]
                      const float* __restrict__ W3, const float* __restrict__ b3,  // [64][64]
                      float* __restrict__ out) {
    __shared__ float Us[64 * LDU];
    __shared__ float W1s[128 * LDP];
    __shared__ float W2s[64 * LDP];
    __shared__ float W3s[64 * LDP];
    __shared__ float Hs[64 * LDP];
    __shared__ float inv1[64], inv2[64];

    const int t = threadIdx.x;
    const int rowbase = blockIdx.x * 64;

    if (t < 64) {
        int g = rowbase + t;
        int c = lower_bound_i(batch1, N1, g + 1) - lower_bound_i(batch1, N1, g);
        inv1[t] = 1.0f / (float)max(c, 1);
    } else if (t < 128) {
        int g = rowbase + (t - 64);
        int c = lower_bound_i(batch2, N2, g + 1) - lower_bound_i(batch2, N2, g);
        inv2[t - 64] = 1.0f / (float)max(c, 1);
    }

    {
        const float4* W1v = (const float4*)W1;
#pragma unroll
        for (int r = 0; r < 8; r++) {
            int e4 = t + 256 * r;
            int e = e4 * 4;
            int k = e / 64, j = e % 64;
            *(float4*)&W1s[k * LDP + j] = W1v[e4];
        }
        const float4* W2v = (const float4*)W2;
        const float4* W3v = (const float4*)W3;
#pragma unroll
        for (int r = 0; r < 4; r++) {
            int e4 = t + 256 * r;
            int e = e4 * 4;
            int k = e / 64, j = e % 64;
            *(float4*)&W2s[k * LDP + j] = W2v[e4];
            *(float4*)&W3s[k * LDP + j] = W3v[e4];
        }
    }
    __syncthreads();

    {
        const float4* nv = (const float4*)(num + (size_t)rowbase * 128);
#pragma unroll
        for (int r = 0; r < 8; r++) {
            int e4 = t + 256 * r;
            int e = e4 * 4;
            int row = e / 128, col = e % 128;
            float4 v = nv[e4];
            float s = (col < 64) ? inv1[row] : inv2[row];
            v.x *= s; v.y *= s; v.z *= s; v.w *= s;
            *(float4*)&Us[row * LDU + col] = v;
        }
    }
    __syncthreads();

    const int fg = t & 15, ng = t >> 4;
    const int j0 = fg * 4, n0 = ng * 4;

    float acc[4][4];
#pragma unroll
    for (int i = 0; i < 4; i++) { acc[i][0] = 0.f; acc[i][1] = 0.f; acc[i][2] = 0.f; acc[i][3] = 0.f; }
    tile_gemm<128, LDU, LDP>(Us, W1s, acc, n0, j0);
    {
        float4 bb = *(const float4*)&b1[j0];
#pragma unroll
        for (int i = 0; i < 4; i++) {
            float4 hv;
            hv.x = fmaxf(acc[i][0] + bb.x, 0.f);
            hv.y = fmaxf(acc[i][1] + bb.y, 0.f);
            hv.z = fmaxf(acc[i][2] + bb.z, 0.f);
            hv.w = fmaxf(acc[i][3] + bb.w, 0.f);
            *(float4*)&Hs[(n0 + i) * LDP + j0] = hv;
        }
    }
    __syncthreads();

#pragma unroll
    for (int i = 0; i < 4; i++) { acc[i][0] = 0.f; acc[i][1] = 0.f; acc[i][2] = 0.f; acc[i][3] = 0.f; }
    tile_gemm<64, LDP, LDP>(Hs, W2s, acc, n0, j0);
    {
        float4 bb = *(const float4*)&b2[j0];
#pragma unroll
        for (int i = 0; i < 4; i++) {
            float4 hv;
            hv.x = fmaxf(acc[i][0] + bb.x, 0.f);
            hv.y = fmaxf(acc[i][1] + bb.y, 0.f);
            hv.z = fmaxf(acc[i][2] + bb.z, 0.f);
            hv.w = fmaxf(acc[i][3] + bb.w, 0.f);
            *(float4*)&Us[(n0 + i) * LDU + j0] = hv;
        }
    }
    __syncthreads();

#pragma unroll
    for (int i = 0; i < 4; i++) { acc[i][0] = 0.f; acc[i][1] = 0.f; acc[i][2] = 0.f; acc[i][3] = 0.f; }
    tile_gemm<64, LDU, LDP>(Us, W3s, acc, n0, j0);
    {
        float4 bb = *(const float4*)&b3[j0];
#pragma unroll
        for (int i = 0; i < 4; i++) {
            float4 ov;
            ov.x = acc[i][0] + bb.x;
            ov.y = acc[i][1] + bb.y;
            ov.z = acc[i][2] + bb.z;
            ov.w = acc[i][3] + bb.w;
            *(float4*)&out[(size_t)(rowbase + n0 + i) * 64 + j0] = ov;
        }
    }
}

extern "C" void kernel_launch(void* const* d_in, const int* in_sizes, int n_in,
                              void* d_out, int out_size, void* d_ws, size_t ws_size,
                              hipStream_t stream) {
    const float* x1     = (const float*)d_in[0];
    const int*   batch1 = (const int*)d_in[1];
    const float* x2     = (const float*)d_in[2];
    const int*   batch2 = (const int*)d_in[3];
    const float* aW1    = (const float*)d_in[4];
    const float* ab1    = (const float*)d_in[5];
    const float* aW2    = (const float*)d_in[6];
    const float* ab2    = (const float*)d_in[7];
    const float* aW3    = (const float*)d_in[8];
    const float* ab3    = (const float*)d_in[9];
    const float* fW1    = (const float*)d_in[10];
    const float* fb1    = (const float*)d_in[11];
    const float* fW2    = (const float*)d_in[12];
    const float* fb2    = (const float*)d_in[13];
    const float* fW3    = (const float*)d_in[14];
    const float* fb3    = (const float*)d_in[15];

    const int N1 = in_sizes[0] / 64;
    const int N2 = in_sizes[2] / 64;

    // ws layout: [w1p 8KB][w2t 8KB][num f32 4096x128 = 2MB]
    unsigned short* w1p = (unsigned short*)d_ws;
    unsigned short* w2t = w1p + 64 * 64;
    float* num = (float*)((char*)d_ws + 16384);

    prep_kernel<<<dim3(16), dim3(256), 0, stream>>>(aW1, aW2, w1p, w2t);
    hipMemsetAsync(num, 0, (size_t)NGRAPHS * 128 * sizeof(float), stream);

    const int nblk1 = (N1 + 255) / 256;
    const int nblk2 = (N2 + 255) / 256;
    attn_scatter_mfma<<<dim3(nblk1 + nblk2), dim3(256), 0, stream>>>(
        x1, batch1, N1, nblk1, x2, batch2, N2,
        w1p, w2t, ab1, ab2, aW3, ab3, num);
    final_mlp_kernel<<<dim3(NGRAPHS / 64), dim3(256), 0, stream>>>(
        num, batch1, N1, batch2, N2, fW1, fb1, fW2, fb2, fW3, fb3, (float*)d_out);
}

// Round 14
// 154.660 us; speedup vs baseline: 1.0591x; 1.0060x over previous
//
#include <hip/hip_runtime.h>

// ObjectMeanDirectAttention — Round 14: full 4-deep x prefetch (all 64 nodes loaded in
// prologue, 16KB/wave in flight, ONE exposed HBM latency per wave instead of 4).
// R13 post-mortem: occupancy capped ~2.8-4 waves/SIMD by hidden MFMA regs; per-q serial
// chain (~700cy x4) is the stall. Buy ILP with registers since occupancy can't rise.
// Everything else unchanged from R13 (f32 LDS coefs, bank-uniform 144B-row tiles).

#define NGRAPHS 4096
constexpr int LDP = 68;    // f32 LDS stride, final MLP
constexpr int LDU = 132;   // f32 LDS stride, 128-wide u tile
constexpr int LDXS = 72;   // bf16 LDS stride (144B rows) for weight + scatter tiles

typedef short bf16x8 __attribute__((ext_vector_type(8)));
typedef float f32x4 __attribute__((ext_vector_type(4)));

union BF8 { bf16x8 v; unsigned u[4]; };

__device__ __forceinline__ unsigned short f2bf(float f) {
    unsigned u = __float_as_uint(f);
    return (unsigned short)((u + 0x7FFFu + ((u >> 16) & 1u)) >> 16);  // RNE
}

__device__ __forceinline__ unsigned cvt_pk_bf16(float lo, float hi) {
    unsigned r;
    asm("v_cvt_pk_bf16_f32 %0, %1, %2" : "=v"(r) : "v"(lo), "v"(hi));
    return r;
}

__device__ __forceinline__ float bflo(unsigned u) { return __uint_as_float(u << 16); }
__device__ __forceinline__ float bfhi(unsigned u) { return __uint_as_float(u & 0xffff0000u); }

__device__ __forceinline__ int lower_bound_i(const int* __restrict__ arr, int n, int v) {
    int lo = 0, hi = n;
    while (lo < hi) {
        int mid = (lo + hi) >> 1;
        if (arr[mid] < v) lo = mid + 1; else hi = mid;
    }
    return lo;
}

// one-shot prep: permuted bf16 weights into ws
__global__ __launch_bounds__(256)
void prep_kernel(const float* __restrict__ W1, const float* __restrict__ W2,
                 unsigned short* __restrict__ w1p, unsigned short* __restrict__ w2t) {
    int e = blockIdx.x * 256 + threadIdx.x;     // 0..4095
    int r = e >> 6, k = e & 63;
    int ct = r >> 4, kb = (r >> 2) & 3, reg = r & 3;
    int pi = 32 * (ct >> 1) + 8 * kb + 4 * (ct & 1) + reg;
    w1p[e] = f2bf(W1[k * 64 + pi]);
    w2t[e] = f2bf(W2[k * 64 + r]);
}

// ---------------- attention MLP + weighted scatter ----------------
__global__ __launch_bounds__(256)
void attn_scatter_mfma(const float* __restrict__ x1, const int* __restrict__ batch1, int N1, int nblk1,
                       const float* __restrict__ x2, const int* __restrict__ batch2, int N2,
                       const unsigned short* __restrict__ w1p, const unsigned short* __restrict__ w2t,
                       const float* __restrict__ b1, const float* __restrict__ b2,
                       const float* __restrict__ W3, const float* __restrict__ b3,
                       float* __restrict__ num) {
    __shared__ alignas(16) unsigned short W1L[64 * LDXS];     // bf16, 144B rows (bank-uniform)
    __shared__ alignas(16) unsigned short W2L[64 * LDXS];
    __shared__ alignas(16) float coefF[192];                  // b1 | b2 | W3 (f32)
    __shared__ alignas(16) unsigned short Xs[4][16 * LDXS];   // per-wave bf16 scatter tile

    const float* x; const int* batch; int N, col_off, blk;
    if ((int)blockIdx.x < nblk1) { x = x1; batch = batch1; N = N1; col_off = 0;  blk = blockIdx.x; }
    else                         { x = x2; batch = batch2; N = N2; col_off = 64; blk = blockIdx.x - nblk1; }

    const int t = threadIdx.x;
    const int w = t >> 6, l = t & 63;
    const int jj = l & 15, kb = l >> 4;
    const int base = blk * 256 + w * 64;          // this wave's 64 nodes

    // ---- full 4-deep x prefetch: issue ALL 16 dwordx4 loads before anything else ----
    float4 xq0[4], xq1[4], xq2[4], xq3[4];
#pragma unroll
    for (int q = 0; q < 4; ++q) {
        const int row = base + q * 16 + jj;
        float4 a0, a1, a2, a3;
        a0 = a1 = a2 = a3 = make_float4(0.f, 0.f, 0.f, 0.f);
        if (row < N) {
            const float* xr = x + (size_t)row * 64;
            a0 = *(const float4*)&xr[kb * 8];
            a1 = *(const float4*)&xr[kb * 8 + 4];
            a2 = *(const float4*)&xr[32 + kb * 8];
            a3 = *(const float4*)&xr[32 + kb * 8 + 4];
        }
        xq0[q] = a0; xq1[q] = a1; xq2[q] = a2; xq3[q] = a3;
    }

    // ---- stage weights (16 KB) + f32 coefficients into LDS (overlaps the x loads) ----
    {
        const uint4* s1 = (const uint4*)w1p;      // 512 chunks of 16B
        const uint4* s2 = (const uint4*)w2t;
#pragma unroll
        for (int r = 0; r < 2; ++r) {
            int e4 = t + 256 * r;                 // 0..511
            int row = e4 >> 3, c4 = e4 & 7;       // row 0..63, 16B-chunk 0..7
            *(uint4*)((char*)W1L + row * 144 + c4 * 16) = s1[e4];
            *(uint4*)((char*)W2L + row * 144 + c4 * 16) = s2[e4];
        }
        if (t < 64)       coefF[t] = b1[t];
        else if (t < 128) coefF[t] = b2[t - 64];
        else if (t < 192) coefF[t] = W3[t - 128];
    }
    __syncthreads();

    const bool wave_valid = (base < N);
    const int nvalid = wave_valid ? min(64, N - base) : 0;

    // ---- batch ids + segment ballot ----
    const int gball = batch[min(base + l, N - 1)];
    const int gprev = __shfl_up(gball, 1);
    const unsigned long long bal = __ballot(l > 0 && gball != gprev);
    const bool slow = (bal != 0ull) || (nvalid < 64);

    const float b3v = b3[0];
    unsigned short* Xw = Xs[w];

    float ac0 = 0.f, ac1 = 0.f, ac2 = 0.f, ac3 = 0.f;   // fast path (4 feats x own nodes)
    float sacc = 0.f;                                    // slow path (feature l)
    int gcur = __shfl(gball, 0);

#pragma unroll
    for (int q = 0; q < 4; ++q) {
        const int nbase = base + q * 16;
        const float4 c0 = xq0[q], c1 = xq1[q], c2 = xq2[q], c3 = xq3[q];

        // ---- convert current q, stash scatter tile ----
        BF8 xb0, xb1;
        xb0.u[0] = cvt_pk_bf16(c0.x, c0.y); xb0.u[1] = cvt_pk_bf16(c0.z, c0.w);
        xb0.u[2] = cvt_pk_bf16(c1.x, c1.y); xb0.u[3] = cvt_pk_bf16(c1.z, c1.w);
        xb1.u[0] = cvt_pk_bf16(c2.x, c2.y); xb1.u[1] = cvt_pk_bf16(c2.z, c2.w);
        xb1.u[2] = cvt_pk_bf16(c3.x, c3.y); xb1.u[3] = cvt_pk_bf16(c3.z, c3.w);
        *(bf16x8*)&Xw[jj * LDXS + kb * 8]      = xb0.v;
        *(bf16x8*)&Xw[jj * LDXS + 32 + kb * 8] = xb1.v;

        // ---- layer 1 (swapped): weights from LDS, bias C-init from f32 LDS ----
        unsigned ph[8];
#pragma unroll
        for (int ct = 0; ct < 4; ++ct) {
            const unsigned short* wr = &W1L[(ct * 16 + jj) * LDXS + kb * 8];
            const bf16x8 wf0 = *(const bf16x8*)wr;
            const bf16x8 wf1 = *(const bf16x8*)(wr + 32);
            f32x4 acc = *(const f32x4*)&coefF[32 * (ct >> 1) + 8 * kb + 4 * (ct & 1)];
            acc = __builtin_amdgcn_mfma_f32_16x16x32_bf16(wf0, xb0.v, acc, 0, 0, 0);
            acc = __builtin_amdgcn_mfma_f32_16x16x32_bf16(wf1, xb1.v, acc, 0, 0, 0);
            ph[2 * ct]     = cvt_pk_bf16(fmaxf(acc[0], 0.f), fmaxf(acc[1], 0.f));
            ph[2 * ct + 1] = cvt_pk_bf16(fmaxf(acc[2], 0.f), fmaxf(acc[3], 0.f));
        }
        BF8 bh0, bh1;
        bh0.u[0] = ph[0]; bh0.u[1] = ph[1]; bh0.u[2] = ph[2]; bh0.u[3] = ph[3];
        bh1.u[0] = ph[4]; bh1.u[1] = ph[5]; bh1.u[2] = ph[6]; bh1.u[3] = ph[7];

        // ---- layer 2+3 (swapped): b2/W3 as f32x4 from LDS ----
        float p = 0.f;
#pragma unroll
        for (int ct = 0; ct < 4; ++ct) {
            const unsigned short* wr = &W2L[(ct * 16 + jj) * LDXS + kb * 8];
            const bf16x8 wf0 = *(const bf16x8*)wr;
            const bf16x8 wf1 = *(const bf16x8*)(wr + 32);
            f32x4 acc = { 0.f, 0.f, 0.f, 0.f };
            acc = __builtin_amdgcn_mfma_f32_16x16x32_bf16(wf0, bh0.v, acc, 0, 0, 0);
            acc = __builtin_amdgcn_mfma_f32_16x16x32_bf16(wf1, bh1.v, acc, 0, 0, 0);
            const f32x4 b2v = *(const f32x4*)&coefF[64 + ct * 16 + 4 * kb];
            const f32x4 w3v = *(const f32x4*)&coefF[128 + ct * 16 + 4 * kb];
            p += fmaxf(acc[0] + b2v[0], 0.f) * w3v[0]
               + fmaxf(acc[1] + b2v[1], 0.f) * w3v[1]
               + fmaxf(acc[2] + b2v[2], 0.f) * w3v[2]
               + fmaxf(acc[3] + b2v[3], 0.f) * w3v[3];
        }
        p += __shfl_xor(p, 16);
        p += __shfl_xor(p, 32);
        const float a = p + b3v;     // a[node jj], all kb copies

        // ---- scatter ----
        if (!slow) {
            // lane (jj,kb): features jj*4..+3, nodes kb*4..+3 of this q-chunk
#pragma unroll
            for (int j = 0; j < 4; ++j) {
                const int row = kb * 4 + j;
                const float aj = __shfl(a, row);
                const uint2 xr2 = *(const uint2*)&Xw[row * LDXS + jj * 4];
                ac0 += bflo(xr2.x) * aj;
                ac1 += bfhi(xr2.x) * aj;
                ac2 += bflo(xr2.y) * aj;
                ac3 += bfhi(xr2.y) * aj;
            }
        } else if (wave_valid) {
            const int lim = min(16, N - nbase);
#pragma unroll
            for (int i = 0; i < 16; ++i) {
                if (i < lim) {                              // wave-uniform
                    const int g = __shfl(gball, q * 16 + i);
                    const float ai = __shfl(a, i);
                    if (g != gcur) {
                        atomicAdd(&num[(size_t)gcur * 128 + col_off + l], sacc);
                        sacc = 0.f;
                        gcur = g;
                    }
                    sacc += __uint_as_float(((unsigned)Xw[i * LDXS + l]) << 16) * ai;
                }
            }
        }
    }

    // ---- final flush ----
    if (!slow) {
        ac0 += __shfl_xor(ac0, 16); ac1 += __shfl_xor(ac1, 16);
        ac2 += __shfl_xor(ac2, 16); ac3 += __shfl_xor(ac3, 16);
        ac0 += __shfl_xor(ac0, 32); ac1 += __shfl_xor(ac1, 32);
        ac2 += __shfl_xor(ac2, 32); ac3 += __shfl_xor(ac3, 32);
        if (kb == 0) {
            const int g = __shfl(gball, 0);
            float* dst = &num[(size_t)g * 128 + col_off + jj * 4];
            atomicAdd(dst + 0, ac0);
            atomicAdd(dst + 1, ac1);
            atomicAdd(dst + 2, ac2);
            atomicAdd(dst + 3, ac3);
        }
    } else if (wave_valid) {
        atomicAdd(&num[(size_t)gcur * 128 + col_off + l], sacc);
    }
}

// ---------------- final MLP (f32, unchanged: negligible time) ----------------
template<int K, int LDAa, int LDBb>
__device__ __forceinline__ void tile_gemm(const float* __restrict__ As,
                                          const float* __restrict__ Bs,
                                          float acc[4][4], int n0, int j0) {
#pragma unroll 4
    for (int k0 = 0; k0 < K; k0 += 4) {
        float4 a[4], wv[4];
#pragma unroll
        for (int i = 0; i < 4; i++) a[i] = *(const float4*)&As[(n0 + i) * LDAa + k0];
#pragma unroll
        for (int kk = 0; kk < 4; kk++) wv[kk] = *(const float4*)&Bs[(k0 + kk) * LDBb + j0];
#pragma unroll
        for (int i = 0; i < 4; i++) {
            const float av0 = a[i].x, av1 = a[i].y, av2 = a[i].z, av3 = a[i].w;
            acc[i][0] += av0 * wv[0].x; acc[i][1] += av0 * wv[0].y; acc[i][2] += av0 * wv[0].z; acc[i][3] += av0 * wv[0].w;
            acc[i][0] += av1 * wv[1].x; acc[i][1] += av1 * wv[1].y; acc[i][2] += av1 * wv[1].z; acc[i][3] += av1 * wv[1].w;
            acc[i][0] += av2 * wv[2].x; acc[i][1] += av2 * wv[2].y; acc[i][2] += av2 * wv[2].z; acc[i][3] += av2 * wv[2].w;
            acc[i][0] += av3 * wv[3].x; acc[i][1] += av3 * wv[3].y; acc[i][2] += av3 * wv[3].z; acc[i][3] += av3 * wv[3].w;
        }
    }
}

__global__ __launch_bounds__(256)
void final_mlp_kernel(const float* __restrict__ num,
                      const int* __restrict__ batch1, int N1,
                      const int* __restrict__ batch2, int N2,
                      const float* __restrict__ W1, const float* __restrict__ b1,  // [128][64]
                      const float* __restrict__ W2, const float* __restrict__ b2,  // [64][64]
                      const float* __restrict__ W3, const float* __restrict__ b3,  // [64][64]
                      float* __restrict__ out) {
    __shared__ float Us[64 * LDU];
    __shared__ float W1s[128 * LDP];
    __shared__ float W2s[64 * LDP];
    __shared__ float W3s[64 * LDP];
    __shared__ float Hs[64 * LDP];
    __shared__ float inv1[64], inv2[64];

    const int t = threadIdx.x;
    const int rowbase = blockIdx.x * 64;

    if (t < 64) {
        int g = rowbase + t;
        int c = lower_bound_i(batch1, N1, g + 1) - lower_bound_i(batch1, N1, g);
        inv1[t] = 1.0f / (float)max(c, 1);
    } else if (t < 128) {
        int g = rowbase + (t - 64);
        int c = lower_bound_i(batch2, N2, g + 1) - lower_bound_i(batch2, N2, g);
        inv2[t - 64] = 1.0f / (float)max(c, 1);
    }

    {
        const float4* W1v = (const float4*)W1;
#pragma unroll
        for (int r = 0; r < 8; r++) {
            int e4 = t + 256 * r;
            int e = e4 * 4;
            int k = e / 64, j = e % 64;
            *(float4*)&W1s[k * LDP + j] = W1v[e4];
        }
        const float4* W2v = (const float4*)W2;
        const float4* W3v = (const float4*)W3;
#pragma unroll
        for (int r = 0; r < 4; r++) {
            int e4 = t + 256 * r;
            int e = e4 * 4;
            int k = e / 64, j = e % 64;
            *(float4*)&W2s[k * LDP + j] = W2v[e4];
            *(float4*)&W3s[k * LDP + j] = W3v[e4];
        }
    }
    __syncthreads();

    {
        const float4* nv = (const float4*)(num + (size_t)rowbase * 128);
#pragma unroll
        for (int r = 0; r < 8; r++) {
            int e4 = t + 256 * r;
            int e = e4 * 4;
            int row = e / 128, col = e % 128;
            float4 v = nv[e4];
            float s = (col < 64) ? inv1[row] : inv2[row];
            v.x *= s; v.y *= s; v.z *= s; v.w *= s;
            *(float4*)&Us[row * LDU + col] = v;
        }
    }
    __syncthreads();

    const int fg = t & 15, ng = t >> 4;
    const int j0 = fg * 4, n0 = ng * 4;

    float acc[4][4];
#pragma unroll
    for (int i = 0; i < 4; i++) { acc[i][0] = 0.f; acc[i][1] = 0.f; acc[i][2] = 0.f; acc[i][3] = 0.f; }
    tile_gemm<128, LDU, LDP>(Us, W1s, acc, n0, j0);
    {
        float4 bb = *(const float4*)&b1[j0];
#pragma unroll
        for (int i = 0; i < 4; i++) {
            float4 hv;
            hv.x = fmaxf(acc[i][0] + bb.x, 0.f);
            hv.y = fmaxf(acc[i][1] + bb.y, 0.f);
            hv.z = fmaxf(acc[i][2] + bb.z, 0.f);
            hv.w = fmaxf(acc[i][3] + bb.w, 0.f);
            *(float4*)&Hs[(n0 + i) * LDP + j0] = hv;
        }
    }
    __syncthreads();

#pragma unroll
    for (int i = 0; i < 4; i++) { acc[i][0] = 0.f; acc[i][1] = 0.f; acc[i][2] = 0.f; acc[i][3] = 0.f; }
    tile_gemm<64, LDP, LDP>(Hs, W2s, acc, n0, j0);
    {
        float4 bb = *(const float4*)&b2[j0];
#pragma unroll
        for (int i = 0; i < 4; i++) {
            float4 hv;
            hv.x = fmaxf(acc[i][0] + bb.x, 0.f);
            hv.y = fmaxf(acc[i][1] + bb.y, 0.f);
            hv.z = fmaxf(acc[i][2] + bb.z, 0.f);
            hv.w = fmaxf(acc[i][3] + bb.w, 0.f);
            *(float4*)&Us[(n0 + i) * LDU + j0] = hv;
        }
    }
    __syncthreads();

#pragma unroll
    for (int i = 0; i < 4; i++) { acc[i][0] = 0.f; acc[i][1] = 0.f; acc[i][2] = 0.f; acc[i][3] = 0.f; }
    tile_gemm<64, LDU, LDP>(Us, W3s, acc, n0, j0);
    {
        float4 bb = *(const float4*)&b3[j0];
#pragma unroll
        for (int i = 0; i < 4; i++) {
            float4 ov;
            ov.x = acc[i][0] + bb.x;
            ov.y = acc[i][1] + bb.y;
            ov.z = acc[i][2] + bb.z;
            ov.w = acc[i][3] + bb.w;
            *(float4*)&out[(size_t)(rowbase + n0 + i) * 64 + j0] = ov;
        }
    }
}

extern "C" void kernel_launch(void* const* d_in, const int* in_sizes, int n_in,
                              void* d_out, int out_size, void* d_ws, size_t ws_size,
                              hipStream_t stream) {
    const float* x1     = (const float*)d_in[0];
    const int*   batch1 = (const int*)d_in[1];
    const float* x2     = (const float*)d_in[2];
    const int*   batch2 = (const int*)d_in[3];
    const float* aW1    = (const float*)d_in[4];
    const float* ab1    = (const float*)d_in[5];
    const float* aW2    = (const float*)d_in[6];
    const float* ab2    = (const float*)d_in[7];
    const float* aW3    = (const float*)d_in[8];
    const float* ab3    = (const float*)d_in[9];
    const float* fW1    = (const float*)d_in[10];
    const float* fb1    = (const float*)d_in[11];
    const float* fW2    = (const float*)d_in[12];
    const float* fb2    = (const float*)d_in[13];
    const float* fW3    = (const float*)d_in[14];
    const float* fb3    = (const float*)d_in[15];

    const int N1 = in_sizes[0] / 64;
    const int N2 = in_sizes[2] / 64;

    // ws layout: [w1p 8KB][w2t 8KB][num f32 4096x128 = 2MB]
    unsigned short* w1p = (unsigned short*)d_ws;
    unsigned short* w2t = w1p + 64 * 64;
    float* num = (float*)((char*)d_ws + 16384);

    prep_kernel<<<dim3(16), dim3(256), 0, stream>>>(aW1, aW2, w1p, w2t);
    hipMemsetAsync(num, 0, (size_t)NGRAPHS * 128 * sizeof(float), stream);

    const int nblk1 = (N1 + 255) / 256;
    const int nblk2 = (N2 + 255) / 256;
    attn_scatter_mfma<<<dim3(nblk1 + nblk2), dim3(256), 0, stream>>>(
        x1, batch1, N1, nblk1, x2, batch2, N2,
        w1p, w2t, ab1, ab2, aW3, ab3, num);
    final_mlp_kernel<<<dim3(NGRAPHS / 64), dim3(256), 0, stream>>>(
        num, batch1, N1, batch2, N2, fW1, fb1, fW2, fb2, fW3, fb3, (float*)d_out);
}